// Round 10
// baseline (57.974 us; speedup 1.0000x reference)
//
#include <hip/hip_runtime.h>
#include <hip/hip_bf16.h>

// logits[b,r,l,t] = sum_h hs[b,l,h]*W[r,t,h] + bias[r,t]; softmax over t(3).
// M = 66048 tokens, K = 768, N = 72 (5 n-tiles of 16, last half-padded).
//
// Round 10: force a REAL pipeline. R9's VGPR=88 proved the compiler
// schedules loads just-in-time after full unroll (declared prefetch depth
// never existed in the .s). This round: (1) B loads issued BEFORE A loads
// each iter (in-order vmcnt drain: consuming B(ks) no longer drains the
// newer A loads), (2) per-iter sched_group_barrier pins emission order
// [VMEM_READ x9][VALU][DS x8][MFMA x10] so loads for ks+2 are issued ahead
// of this iter's waits, (3) depth 2 on both streams, live regs ~126 so
// __launch_bounds__(64,2) keeps 8 waves/CU. Geometry: 32 tok/wave, 2064
// one-wave blocks (known-best). A path: per-lane-contiguous 32B loads,
// HW cvt -> bf16, verified ds_bpermute map src = 4*(t&15)+(t>>4).
// B preconverted bf16 frag-order in d_ws (conv_w_kernel, L2-resident).

#define HD     768
#define LSEQ   8256
#define RREL   24
#define KSTEPS 24      // 768/32
#define NT     5       // n-tiles of 16 covering 72 (tile 4 half-padded)
#define NCOL   72

typedef float f32x4 __attribute__((ext_vector_type(4)));
typedef short s16x8 __attribute__((ext_vector_type(8)));
typedef int   i32x4 __attribute__((ext_vector_type(4)));

__device__ __forceinline__ unsigned f2bf_rne(float f) {  // conv_w only
  unsigned u = __builtin_bit_cast(unsigned, f);
  u += 0x7FFFu + ((u >> 16) & 1u);
  return u >> 16;
}

// hot path: HW cvt (RNE); packed dword via integer ops
__device__ __forceinline__ int pack2(float lo, float hi) {
  unsigned l = __bfloat16_as_ushort(__float2bfloat16(lo));
  unsigned h = __bfloat16_as_ushort(__float2bfloat16(hi));
  return (int)(l | (h << 16));
}

// ---- kernel 1: W (24,3,768) fp32 -> bf16 fragment-order ws ----
// ws chunk idx = (ks*NT + nt)*64 + lane, holding 8 bf16:
//   col = nt*16 + (lane&15), k = ks*32 + (lane>>4)*8 + i   (0 if col>=72)
__global__ void conv_w_kernel(const float* __restrict__ W,
                              unsigned short* __restrict__ wsB) {
  int idx = blockIdx.x * 256 + threadIdx.x;       // [0, 7680)
  if (idx >= KSTEPS * NT * 64) return;
  int ks   = idx / (NT * 64);
  int rem  = idx - ks * (NT * 64);
  int nt   = rem >> 6;
  int lane = rem & 63;
  int col  = nt * 16 + (lane & 15);
  int k0   = ks * 32 + (lane >> 4) * 8;
  unsigned short v[8] = {0, 0, 0, 0, 0, 0, 0, 0};
  if (col < NCOL) {
    const float* p = W + (size_t)col * HD + k0;
    float4 a = *(const float4*)p;
    float4 b = *(const float4*)(p + 4);
    v[0] = (unsigned short)f2bf_rne(a.x); v[1] = (unsigned short)f2bf_rne(a.y);
    v[2] = (unsigned short)f2bf_rne(a.z); v[3] = (unsigned short)f2bf_rne(a.w);
    v[4] = (unsigned short)f2bf_rne(b.x); v[5] = (unsigned short)f2bf_rne(b.y);
    v[6] = (unsigned short)f2bf_rne(b.z); v[7] = (unsigned short)f2bf_rne(b.w);
  }
  *(s16x8*)(wsB + (size_t)idx * 8) = *(s16x8*)v;
}

// ---- main: 32 tok/wave, 1-wave blocks, pinned pipeline ----
#define ALOAD(ks) do { if ((ks) < KSTEPS) {                        \
    const int s_ = (ks) % 3, o_ = (ks) * 32;                       \
    abuf[s_][0][0] = *(const float4*)(pA0 + o_);                   \
    abuf[s_][0][1] = *(const float4*)(pA0 + o_ + 4);               \
    abuf[s_][1][0] = *(const float4*)(pA1 + o_);                   \
    abuf[s_][1][1] = *(const float4*)(pA1 + o_ + 4);               \
  } } while (0)

#define BLOAD_WS(ks) do { if ((ks) < KSTEPS) {                     \
    _Pragma("unroll")                                              \
    for (int nt_ = 0; nt_ < NT; ++nt_)                             \
      bbuf[(ks) % 3][nt_] = pWS[(ks) * NT * 64 + nt_ * 64 + lane]; \
  } } while (0)

__global__ __launch_bounds__(64, 2)
void tagging_pin(const float* __restrict__ hs, const float* __restrict__ bias,
                 const i32x4* __restrict__ pWS, float* __restrict__ out) {
  __shared__ float lg[32][85];        // stride 85 (21 mod 32): softmax
                                      // column reads conflict-free

  const int lane = threadIdx.x;       // one wave per block
  const int m0   = blockIdx.x * 32;   // 66048/32 = 2064 blocks exact

  const float* pA0 = hs + (size_t)(m0 + (lane >> 2)) * HD + (lane & 3) * 8;
  const float* pA1 = pA0 + 16 * HD;
  // bpermute byte addr: target lane t pulls src lane 4*(t&15) + (t>>4)
  const int bp = ((lane & 15) * 4 + (lane >> 4)) * 4;

  f32x4  acc[2][NT] = {};             // 40 VGPR
  float4 abuf[3][2][2];               // A depth-2 (2 live slots = 32 VGPR)
  i32x4  bbuf[3][NT];                 // B depth-2 (2 live slots = 40 VGPR)

  // prologue: B first, then A (same order discipline as the loop)
  BLOAD_WS(0); BLOAD_WS(1);
  ALOAD(0); ALOAD(1);

  #pragma unroll
  for (int ks = 0; ks < KSTEPS; ++ks) {
    // issue next loads FIRST: B before A (vmcnt is in-order; consuming
    // B(ks) then leaves A(ks+1),A(ks+2) in flight instead of draining them)
    BLOAD_WS(ks + 2);
    ALOAD(ks + 2);
    // pin emission: loads of this iter BEFORE the compute that waits on
    // older loads -> defeats the scheduler's just-in-time load sinking
    __builtin_amdgcn_sched_group_barrier(0x020, 9, 0);   // VMEM_READ x9
    __builtin_amdgcn_sched_group_barrier(0x002, 16, 0);  // VALU (cvt/pack)
    __builtin_amdgcn_sched_group_barrier(0x180, 8, 0);   // DS read (bpermute)
    __builtin_amdgcn_sched_group_barrier(0x008, 10, 0);  // MFMA x10

    s16x8 af[2];
    #pragma unroll
    for (int mt = 0; mt < 2; ++mt) {
      float4 a0 = abuf[ks % 3][mt][0], a1 = abuf[ks % 3][mt][1];
      i32x4 av;
      av[0] = __builtin_amdgcn_ds_bpermute(bp, pack2(a0.x, a0.y));
      av[1] = __builtin_amdgcn_ds_bpermute(bp, pack2(a0.z, a0.w));
      av[2] = __builtin_amdgcn_ds_bpermute(bp, pack2(a1.x, a1.y));
      av[3] = __builtin_amdgcn_ds_bpermute(bp, pack2(a1.z, a1.w));
      af[mt] = __builtin_bit_cast(s16x8, av);
    }

    #pragma unroll
    for (int nt = 0; nt < NT; ++nt) {
      s16x8 bf = __builtin_bit_cast(s16x8, bbuf[ks % 3][nt]);
      acc[0][nt] = __builtin_amdgcn_mfma_f32_16x16x32_bf16(af[0], bf, acc[0][nt], 0, 0, 0);
      acc[1][nt] = __builtin_amdgcn_mfma_f32_16x16x32_bf16(af[1], bf, acc[1][nt], 0, 0, 0);
    }
  }

  // ---- epilogue: wave-private LDS transpose + 3-wide softmax ----
  #pragma unroll
  for (int mt = 0; mt < 2; ++mt)
    #pragma unroll
    for (int nt = 0; nt < NT; ++nt)
      #pragma unroll
      for (int j = 0; j < 4; ++j)     // C/D: col = lane&15, row = 4*(lane>>4)+j
        lg[mt * 16 + (lane >> 4) * 4 + j][nt * 16 + (lane & 15)] = acc[mt][nt][j];
  __syncthreads();                    // single wave: just the lgkmcnt drain

  const int bidx = m0 / LSEQ;         // block-uniform: 8256 % 32 == 0
  const int l0   = m0 - bidx * LSEQ;
  #pragma unroll
  for (int it = 0; it < 12; ++it) {
    int flat = it * 64 + lane;        // [0,768) = 24 relations x 32 tokens
    int g    = flat >> 5;             // relation, half-wave-uniform
    int tokl = flat & 31;
    float x0 = lg[tokl][3 * g + 0] + bias[3 * g + 0];
    float x1 = lg[tokl][3 * g + 1] + bias[3 * g + 1];
    float x2 = lg[tokl][3 * g + 2] + bias[3 * g + 2];
    float mx = fmaxf(x0, fmaxf(x1, x2));
    float e0 = __expf(x0 - mx), e1 = __expf(x1 - mx), e2 = __expf(x2 - mx);
    float inv = 1.0f / (e0 + e1 + e2);
    size_t o = ((size_t)(bidx * RREL + g) * LSEQ + l0 + tokl) * 3;
    out[o + 0] = e0 * inv;
    out[o + 1] = e1 * inv;
    out[o + 2] = e2 * inv;
  }
}

// ---- fallback (no ws): R5-style 1-wave kernel, direct frag-order W loads ----
__global__ __launch_bounds__(64, 2)
void tagging_fb(const float* __restrict__ hs, const float* __restrict__ W,
                const float* __restrict__ bias, float* __restrict__ out) {
  __shared__ float lg[32][85];
  const int lane = threadIdx.x;
  const int m0   = blockIdx.x * 32;

  const float* pA0 = hs + (size_t)(m0 + (lane >> 2)) * HD + (lane & 3) * 8;
  const float* pA1 = pA0 + 16 * HD;
  const int bp = ((lane & 15) * 4 + (lane >> 4)) * 4;

  const float* pB[NT];
  #pragma unroll
  for (int nt = 0; nt < NT; ++nt)
    pB[nt] = W + (size_t)(nt * 16 + (lane & 15)) * HD + (lane >> 4) * 8;
  const bool b4ok = (lane & 15) < 8;

  f32x4  acc[2][NT] = {};
  float4 abuf[3][2][2];
  float4 fbf[2][NT][2];

#define FB_BLOAD(ks) do { if ((ks) < KSTEPS) {                     \
    _Pragma("unroll")                                              \
    for (int nt_ = 0; nt_ < 4; ++nt_) {                            \
      fbf[(ks) & 1][nt_][0] = *(const float4*)(pB[nt_] + (ks)*32); \
      fbf[(ks) & 1][nt_][1] = *(const float4*)(pB[nt_] + (ks)*32 + 4); \
    }                                                              \
    if (b4ok) {                                                    \
      fbf[(ks) & 1][4][0] = *(const float4*)(pB[4] + (ks)*32);     \
      fbf[(ks) & 1][4][1] = *(const float4*)(pB[4] + (ks)*32 + 4); \
    } else {                                                       \
      fbf[(ks) & 1][4][0] = make_float4(0.f,0.f,0.f,0.f);          \
      fbf[(ks) & 1][4][1] = make_float4(0.f,0.f,0.f,0.f);          \
    }                                                              \
  } } while (0)

  FB_BLOAD(0);
  ALOAD(0); ALOAD(1);

  #pragma unroll
  for (int ks = 0; ks < KSTEPS; ++ks) {
    FB_BLOAD(ks + 1);
    ALOAD(ks + 2);
    s16x8 af[2];
    #pragma unroll
    for (int mt = 0; mt < 2; ++mt) {
      float4 a0 = abuf[ks % 3][mt][0], a1 = abuf[ks % 3][mt][1];
      i32x4 av;
      av[0] = __builtin_amdgcn_ds_bpermute(bp, pack2(a0.x, a0.y));
      av[1] = __builtin_amdgcn_ds_bpermute(bp, pack2(a0.z, a0.w));
      av[2] = __builtin_amdgcn_ds_bpermute(bp, pack2(a1.x, a1.y));
      av[3] = __builtin_amdgcn_ds_bpermute(bp, pack2(a1.z, a1.w));
      af[mt] = __builtin_bit_cast(s16x8, av);
    }
    #pragma unroll
    for (int nt = 0; nt < NT; ++nt) {
      float4 b0 = fbf[ks & 1][nt][0], b1 = fbf[ks & 1][nt][1];
      i32x4 bv;
      bv[0] = pack2(b0.x, b0.y); bv[1] = pack2(b0.z, b0.w);
      bv[2] = pack2(b1.x, b1.y); bv[3] = pack2(b1.z, b1.w);
      s16x8 bf = __builtin_bit_cast(s16x8, bv);
      acc[0][nt] = __builtin_amdgcn_mfma_f32_16x16x32_bf16(af[0], bf, acc[0][nt], 0, 0, 0);
      acc[1][nt] = __builtin_amdgcn_mfma_f32_16x16x32_bf16(af[1], bf, acc[1][nt], 0, 0, 0);
    }
  }

  #pragma unroll
  for (int mt = 0; mt < 2; ++mt)
    #pragma unroll
    for (int nt = 0; nt < NT; ++nt)
      #pragma unroll
      for (int j = 0; j < 4; ++j)
        lg[mt * 16 + (lane >> 4) * 4 + j][nt * 16 + (lane & 15)] = acc[mt][nt][j];
  __syncthreads();

  const int bidx = m0 / LSEQ;
  const int l0   = m0 - bidx * LSEQ;
  #pragma unroll
  for (int it = 0; it < 12; ++it) {
    int flat = it * 64 + lane;
    int g    = flat >> 5;
    int tokl = flat & 31;
    float x0 = lg[tokl][3 * g + 0] + bias[3 * g + 0];
    float x1 = lg[tokl][3 * g + 1] + bias[3 * g + 1];
    float x2 = lg[tokl][3 * g + 2] + bias[3 * g + 2];
    float mx = fmaxf(x0, fmaxf(x1, x2));
    float e0 = __expf(x0 - mx), e1 = __expf(x1 - mx), e2 = __expf(x2 - mx);
    float inv = 1.0f / (e0 + e1 + e2);
    size_t o = ((size_t)(bidx * RREL + g) * LSEQ + l0 + tokl) * 3;
    out[o + 0] = e0 * inv;
    out[o + 1] = e1 * inv;
    out[o + 2] = e2 * inv;
  }
}

extern "C" void kernel_launch(void* const* d_in, const int* in_sizes, int n_in,
                              void* d_out, int out_size, void* d_ws, size_t ws_size,
                              hipStream_t stream) {
  (void)in_sizes; (void)n_in; (void)out_size;
  const float* hs   = (const float*)d_in[0];  // (8, 8256, 768) fp32
  const float* W    = (const float*)d_in[1];  // (24, 3, 768)   fp32
  const float* bias = (const float*)d_in[2];  // (24, 3)        fp32
  float* out = (float*)d_out;                 // (8, 24, 8256, 3) fp32

  const size_t needB = (size_t)KSTEPS * NT * 64 * 8 * 2;   // 122880 B
  if (d_ws && ws_size >= needB) {
    hipLaunchKernelGGL(conv_w_kernel, dim3(30), dim3(256), 0, stream,
                       W, (unsigned short*)d_ws);
    hipLaunchKernelGGL(tagging_pin, dim3(2064), dim3(64), 0, stream,
                       hs, bias, (const i32x4*)d_ws, out);
  } else {
    hipLaunchKernelGGL(tagging_fb, dim3(2064), dim3(64), 0, stream,
                       hs, W, bias, out);
  }
}

// Round 11
// 46.426 us; speedup vs baseline: 1.2487x; 1.2487x over previous
//
#include <hip/hip_runtime.h>
#include <hip/hip_bf16.h>

// logits[b,r,l,t] = sum_h hs[b,l,h]*W[r,t,h] + bias[r,t]; softmax over t(3).
// M = 66048 tokens, K = 768, N = 72 (5 n-tiles of 16, last half-padded).
//
// FINAL (= round-6 kernel, measured 46.4 us; restored after R7-R10
// structural experiments all regressed). Structure:
//  - conv_w_kernel: W fp32 -> bf16 MFMA-fragment-order into d_ws (120 KB,
//    L2-resident) so main-kernel B loads are lane-contiguous dwordx4.
//  - tagging_main: barrier-free 1-wave blocks, 32 tokens/wave, 2064 blocks
//    (8 waves/CU). A loaded per-lane-contiguous (32B/lane per 16-row
//    phase), HW v_cvt fp32->bf16, redistributed to MFMA fragment order via
//    ds_bpermute (verified map: src = 4*(t&15) + (t>>4)). K-loop fully
//    unrolled; compiler JIT-schedules loads (measured: declared prefetch
//    depth does not survive codegen, and fighting it regresses).
//  - Epilogue: wave-private LDS transpose (stride 85, conflict-free),
//    3-wide softmax, 12B-contiguous coalesced stores.
// Measured equilibrium: ~5.35 TB/s effective on 222 MB mandatory traffic
// + ~4.5 us two-kernel serialization. Levers measured null/negative:
// prefetch depth (R6), LDS-B staging (R7, -17%), K-split TLP (R8, -20%),
// 64-tok waves (R9, -5%), sched_group_barrier pinning (R10, -25%).

#define HD     768
#define LSEQ   8256
#define RREL   24
#define KSTEPS 24      // 768/32
#define NT     5       // n-tiles of 16 covering 72 (tile 4 half-padded)
#define NCOL   72

typedef float f32x4 __attribute__((ext_vector_type(4)));
typedef short s16x8 __attribute__((ext_vector_type(8)));
typedef int   i32x4 __attribute__((ext_vector_type(4)));

__device__ __forceinline__ unsigned f2bf_rne(float f) {  // used in conv_w only
  unsigned u = __builtin_bit_cast(unsigned, f);
  u += 0x7FFFu + ((u >> 16) & 1u);
  return u >> 16;
}

// hot path: HW cvt (RNE); build packed dword with integer ops
__device__ __forceinline__ int pack2(float lo, float hi) {
  unsigned l = __bfloat16_as_ushort(__float2bfloat16(lo));
  unsigned h = __bfloat16_as_ushort(__float2bfloat16(hi));
  return (int)(l | (h << 16));
}

// ---- kernel 1: W (24,3,768) fp32 -> bf16 fragment-order ws ----
// ws element idx = (ks*NT + nt)*64 + lane, holding 8 bf16:
//   col = nt*16 + (lane&15), k = ks*32 + (lane>>4)*8 + i   (0 if col>=72)
__global__ void conv_w_kernel(const float* __restrict__ W,
                              unsigned short* __restrict__ wsB) {
  int idx = blockIdx.x * 256 + threadIdx.x;       // [0, 7680)
  if (idx >= KSTEPS * NT * 64) return;
  int ks   = idx / (NT * 64);
  int rem  = idx - ks * (NT * 64);
  int nt   = rem >> 6;
  int lane = rem & 63;
  int col  = nt * 16 + (lane & 15);
  int k0   = ks * 32 + (lane >> 4) * 8;
  unsigned short v[8] = {0, 0, 0, 0, 0, 0, 0, 0};
  if (col < NCOL) {
    const float* p = W + (size_t)col * HD + k0;
    float4 a = *(const float4*)p;
    float4 b = *(const float4*)(p + 4);
    v[0] = (unsigned short)f2bf_rne(a.x); v[1] = (unsigned short)f2bf_rne(a.y);
    v[2] = (unsigned short)f2bf_rne(a.z); v[3] = (unsigned short)f2bf_rne(a.w);
    v[4] = (unsigned short)f2bf_rne(b.x); v[5] = (unsigned short)f2bf_rne(b.y);
    v[6] = (unsigned short)f2bf_rne(b.z); v[7] = (unsigned short)f2bf_rne(b.w);
  }
  *(s16x8*)(wsB + (size_t)idx * 8) = *(s16x8*)v;
}

// ---- main kernel ----
// A slot load: two 16-row phases (one per m-frag), lane-contiguous 32B each:
// phase p covers rows m0+16p+(lane>>2), floats (ks*32)+(lane&3)*8 .. +8.
#define ALOAD(ks) do { if ((ks) < KSTEPS) {                        \
    const int s_ = (ks) % 5, o_ = (ks) * 32;                       \
    abuf[s_][0][0] = *(const float4*)(pA0 + o_);                   \
    abuf[s_][0][1] = *(const float4*)(pA0 + o_ + 4);               \
    abuf[s_][1][0] = *(const float4*)(pA1 + o_);                   \
    abuf[s_][1][1] = *(const float4*)(pA1 + o_ + 4);               \
  } } while (0)

#define BLOAD_WS(ks) do { if ((ks) < KSTEPS) {                     \
    _Pragma("unroll")                                              \
    for (int nt_ = 0; nt_ < NT; ++nt_)                             \
      bbuf[(ks) % 3][nt_] = pWS[(ks) * NT * 64 + nt_ * 64 + lane]; \
  } } while (0)

#define BLOAD_FB(ks) do { if ((ks) < KSTEPS) {                     \
    _Pragma("unroll")                                              \
    for (int nt_ = 0; nt_ < 4; ++nt_) {                            \
      fbf[(ks) & 1][nt_][0] = *(const float4*)(pB[nt_] + (ks)*32); \
      fbf[(ks) & 1][nt_][1] = *(const float4*)(pB[nt_] + (ks)*32 + 4); \
    }                                                              \
    if (b4ok) {                                                    \
      fbf[(ks) & 1][4][0] = *(const float4*)(pB[4] + (ks)*32);     \
      fbf[(ks) & 1][4][1] = *(const float4*)(pB[4] + (ks)*32 + 4); \
    } else {                                                       \
      fbf[(ks) & 1][4][0] = make_float4(0.f,0.f,0.f,0.f);          \
      fbf[(ks) & 1][4][1] = make_float4(0.f,0.f,0.f,0.f);          \
    }                                                              \
  } } while (0)

template <bool USE_WS>
__global__ __launch_bounds__(64, 2)
void tagging_main(const float* __restrict__ hs, const float* __restrict__ W,
                  const float* __restrict__ bias,
                  const i32x4* __restrict__ pWS, float* __restrict__ out) {
  __shared__ float lg[32][85];        // stride 85 (gcd(85,32)=1): softmax
                                      // column reads conflict-free

  const int lane = threadIdx.x;       // one wave per block
  const int m0   = blockIdx.x * 32;   // 66048/32 = 2064 blocks, exact

  const float* pA0 = hs + (size_t)(m0 + (lane >> 2)) * HD + (lane & 3) * 8;
  const float* pA1 = pA0 + 16 * HD;
  // bpermute byte addr: target lane t pulls src lane 4*(t&15) + (t>>4)
  const int bp = ((lane & 15) * 4 + (lane >> 4)) * 4;

  // fallback B pointers (fragment-order scatter, only if !USE_WS)
  const float* pB[NT];
  #pragma unroll
  for (int nt = 0; nt < NT; ++nt)
    pB[nt] = W + (size_t)(nt * 16 + (lane & 15)) * HD + (lane >> 4) * 8;
  const bool b4ok = (lane & 15) < 8;

  f32x4  acc[2][NT] = {};             // 40 VGPR
  float4 abuf[5][2][2];               // A rotating slots
  i32x4  bbuf[3][NT];                 // B rotating slots (ws path)
  float4 fbf[2][NT][2];               // B slots (fallback path)

  ALOAD(0); ALOAD(1); ALOAD(2); ALOAD(3);
  if constexpr (USE_WS) { BLOAD_WS(0); BLOAD_WS(1); } else { BLOAD_FB(0); }

  #pragma unroll
  for (int ks = 0; ks < KSTEPS; ++ks) {
    ALOAD(ks + 4);
    if constexpr (USE_WS) { BLOAD_WS(ks + 2); } else { BLOAD_FB(ks + 1); }

    s16x8 af[2];
    #pragma unroll
    for (int mt = 0; mt < 2; ++mt) {
      float4 a0 = abuf[ks % 5][mt][0], a1 = abuf[ks % 5][mt][1];
      i32x4 av;
      av[0] = __builtin_amdgcn_ds_bpermute(bp, pack2(a0.x, a0.y));
      av[1] = __builtin_amdgcn_ds_bpermute(bp, pack2(a0.z, a0.w));
      av[2] = __builtin_amdgcn_ds_bpermute(bp, pack2(a1.x, a1.y));
      av[3] = __builtin_amdgcn_ds_bpermute(bp, pack2(a1.z, a1.w));
      af[mt] = __builtin_bit_cast(s16x8, av);
    }

    #pragma unroll
    for (int nt = 0; nt < NT; ++nt) {
      s16x8 bf;
      if constexpr (USE_WS) {
        bf = __builtin_bit_cast(s16x8, bbuf[ks % 3][nt]);
      } else {
        float4 b0 = fbf[ks & 1][nt][0], b1 = fbf[ks & 1][nt][1];
        i32x4 bv;
        bv[0] = pack2(b0.x, b0.y); bv[1] = pack2(b0.z, b0.w);
        bv[2] = pack2(b1.x, b1.y); bv[3] = pack2(b1.z, b1.w);
        bf = __builtin_bit_cast(s16x8, bv);
      }
      acc[0][nt] = __builtin_amdgcn_mfma_f32_16x16x32_bf16(af[0], bf, acc[0][nt], 0, 0, 0);
      acc[1][nt] = __builtin_amdgcn_mfma_f32_16x16x32_bf16(af[1], bf, acc[1][nt], 0, 0, 0);
    }
  }

  // ---- epilogue: wave-private LDS transpose + 3-wide softmax ----
  #pragma unroll
  for (int mt = 0; mt < 2; ++mt)
    #pragma unroll
    for (int nt = 0; nt < NT; ++nt)
      #pragma unroll
      for (int j = 0; j < 4; ++j)   // C/D: col = lane&15, row = 4*(lane>>4)+j
        lg[mt * 16 + (lane >> 4) * 4 + j][nt * 16 + (lane & 15)] = acc[mt][nt][j];
  __syncthreads();                  // single wave: just the lgkmcnt drain

  const int bidx = m0 / LSEQ;       // block-uniform: 8256 % 32 == 0
  const int l0   = m0 - bidx * LSEQ;
  #pragma unroll
  for (int it = 0; it < 12; ++it) {
    int flat = it * 64 + lane;      // [0,768) = 24 relations x 32 tokens
    int g    = flat >> 5;           // relation, half-wave-uniform
    int tokl = flat & 31;
    float x0 = lg[tokl][3 * g + 0] + bias[3 * g + 0];
    float x1 = lg[tokl][3 * g + 1] + bias[3 * g + 1];
    float x2 = lg[tokl][3 * g + 2] + bias[3 * g + 2];
    float mx = fmaxf(x0, fmaxf(x1, x2));
    float e0 = __expf(x0 - mx), e1 = __expf(x1 - mx), e2 = __expf(x2 - mx);
    float inv = 1.0f / (e0 + e1 + e2);
    size_t o = ((size_t)(bidx * RREL + g) * LSEQ + l0 + tokl) * 3;
    out[o + 0] = e0 * inv;
    out[o + 1] = e1 * inv;
    out[o + 2] = e2 * inv;
  }
}

extern "C" void kernel_launch(void* const* d_in, const int* in_sizes, int n_in,
                              void* d_out, int out_size, void* d_ws, size_t ws_size,
                              hipStream_t stream) {
  (void)in_sizes; (void)n_in; (void)out_size;
  const float* hs   = (const float*)d_in[0];  // (8, 8256, 768) fp32
  const float* W    = (const float*)d_in[1];  // (24, 3, 768)   fp32
  const float* bias = (const float*)d_in[2];  // (24, 3)        fp32
  float* out = (float*)d_out;                 // (8, 24, 8256, 3) fp32

  const size_t needB = (size_t)KSTEPS * NT * 64 * 8 * 2;   // 122880 B
  if (d_ws && ws_size >= needB) {
    hipLaunchKernelGGL(conv_w_kernel, dim3(30), dim3(256), 0, stream,
                       W, (unsigned short*)d_ws);
    hipLaunchKernelGGL((tagging_main<true>), dim3(2064), dim3(64), 0, stream,
                       hs, W, bias, (const i32x4*)d_ws, out);
  } else {
    hipLaunchKernelGGL((tagging_main<false>), dim3(2064), dim3(64), 0, stream,
                       hs, W, bias, nullptr, out);
  }
}